// Round 1
// baseline (288.886 us; speedup 1.0000x reference)
//
#include <hip/hip_runtime.h>
#include <hip/hip_bf16.h>

#define NN 16384
#define CD 32   // B*FNEW packed columns

typedef __attribute__((ext_vector_type(4))) float  f32x4;
typedef __attribute__((ext_vector_type(8))) short  s16x8;

__device__ inline short bf16_of(float f) {
    return __builtin_bit_cast(short, __float2bfloat16(f));
}

// Kernel 1: HpT[c][m] (bf16), c = b*16+g.  h[b,m,g] = sum_f x[b,m,f]*ker[m,f,g]
__global__ void fuse_h(const float* __restrict__ x, const float* __restrict__ ker,
                       __hip_bfloat16* __restrict__ hpt) {
    int tid = blockIdx.x * 256 + threadIdx.x;
    int g = tid & 15;
    int m = tid >> 4;            // 0..16383
    const float* xb0 = x + m * 16;
    const float* xb1 = x + NN * 16 + m * 16;
    const float* kp  = ker + m * 256 + g;
    float h0 = 0.f, h1 = 0.f;
#pragma unroll
    for (int f = 0; f < 16; ++f) {
        float kk = kp[f * 16];
        h0 += xb0[f] * kk;
        h1 += xb1[f] * kk;
    }
    hpt[g * NN + m]        = __float2bfloat16(h0);
    hpt[(16 + g) * NN + m] = __float2bfloat16(h1);
}

// Kernel 2: out[b,n,g] = sum_m A[n,m]*Hp[m,c] + bias[n,g]
// Block: 256 thr = 4 waves; block owns 16 rows; wave w handles K-slice [w*4096, (w+1)*4096)
__global__ __launch_bounds__(256, 4) void gcn_main(
        const float* __restrict__ A,
        const __hip_bfloat16* __restrict__ hpt,
        const float* __restrict__ bias,
        float* __restrict__ out) {
    __shared__ float red[4][16][32];

    const int lane = threadIdx.x & 63;
    const int wave = threadIdx.x >> 6;
    const int n0   = blockIdx.x * 16;
    const int row  = lane & 15;          // A row within tile / B col within tile
    const int kg   = lane >> 4;          // 0..3 k-group

    f32x4 acc0 = {0.f, 0.f, 0.f, 0.f};
    f32x4 acc1 = {0.f, 0.f, 0.f, 0.f};

    const int kbase = wave * 4096;
    const float* ap = A + (size_t)(n0 + row) * NN + kbase + kg * 8;
    const __hip_bfloat16* b0 = hpt + row * NN + kbase + kg * 8;        // col-tile 0 (b=0)
    const __hip_bfloat16* b1 = hpt + (16 + row) * NN + kbase + kg * 8; // col-tile 1 (b=1)

    for (int kk = 0; kk < 4096; kk += 64) {
        // A fragments (fp32 -> bf16) for two k-steps of 32
        f32x4 p0 = *(const f32x4*)(ap);
        f32x4 p1 = *(const f32x4*)(ap + 4);
        f32x4 p2 = *(const f32x4*)(ap + 32);
        f32x4 p3 = *(const f32x4*)(ap + 36);
        s16x8 a0, a1;
#pragma unroll
        for (int i = 0; i < 4; ++i) {
            a0[i]     = bf16_of(p0[i]);
            a0[4 + i] = bf16_of(p1[i]);
            a1[i]     = bf16_of(p2[i]);
            a1[4 + i] = bf16_of(p3[i]);
        }
        // B fragments: single b128 loads from transposed bf16 HpT
        s16x8 b00 = *(const s16x8*)(b0);
        s16x8 b01 = *(const s16x8*)(b0 + 32);
        s16x8 b10 = *(const s16x8*)(b1);
        s16x8 b11 = *(const s16x8*)(b1 + 32);

        acc0 = __builtin_amdgcn_mfma_f32_16x16x32_bf16(a0, b00, acc0, 0, 0, 0);
        acc1 = __builtin_amdgcn_mfma_f32_16x16x32_bf16(a0, b10, acc1, 0, 0, 0);
        acc0 = __builtin_amdgcn_mfma_f32_16x16x32_bf16(a1, b01, acc0, 0, 0, 0);
        acc1 = __builtin_amdgcn_mfma_f32_16x16x32_bf16(a1, b11, acc1, 0, 0, 0);

        ap += 64; b0 += 64; b1 += 64;
    }

    // D mapping: col = lane&15, row = (lane>>4)*4 + i
    const int r0 = kg * 4;
#pragma unroll
    for (int i = 0; i < 4; ++i) {
        red[wave][r0 + i][row]      = acc0[i];
        red[wave][r0 + i][16 + row] = acc1[i];
    }
    __syncthreads();

    for (int o = threadIdx.x; o < 512; o += 256) {
        int r = o >> 5, c = o & 31;
        float s = red[0][r][c] + red[1][r][c] + red[2][r][c] + red[3][r][c];
        int b = c >> 4, g = c & 15;
        int n = n0 + r;
        out[(size_t)b * (NN * 16) + n * 16 + g] = s + bias[n * 16 + g];
    }
}

extern "C" void kernel_launch(void* const* d_in, const int* in_sizes, int n_in,
                              void* d_out, int out_size, void* d_ws, size_t ws_size,
                              hipStream_t stream) {
    const float* x    = (const float*)d_in[0];
    const float* A    = (const float*)d_in[1];
    const float* ker  = (const float*)d_in[2];
    const float* bias = (const float*)d_in[3];
    float* out = (float*)d_out;
    __hip_bfloat16* hpt = (__hip_bfloat16*)d_ws;   // 32*16384*2B = 1 MB

    fuse_h<<<dim3(NN * 16 / 256), dim3(256), 0, stream>>>(x, ker, hpt);
    gcn_main<<<dim3(NN / 16), dim3(256), 0, stream>>>(A, hpt, bias, out);
}